// Round 1
// 1411.873 us; speedup vs baseline: 1.8544x; 1.8544x over previous
//
#include <hip/hip_runtime.h>
#include <hip/hip_fp16.h>
#include <cmath>

typedef unsigned short u16;
typedef short v8s __attribute__((ext_vector_type(8)));
typedef float v4f __attribute__((ext_vector_type(4)));

#define B_   8
#define L_   4096
#define D_   1024
#define M_   32768
#define RCAP 8192

// ---------------------------------------------------------------------------
// fp32 -> bf16 hi/lo split (RN on both; lo = a - hi exact by Sterbenz)
// ---------------------------------------------------------------------------
__device__ __forceinline__ void split2(float a, u16& h, u16& l) {
  unsigned ab = __float_as_uint(a);
  unsigned hb = (ab + 0x8000u) & 0xFFFF0000u;
  float hf = __uint_as_float(hb);
  float lf = a - hf;
  h = (u16)(hb >> 16);
  l = (u16)((__float_as_uint(lf) + 0x8000u) >> 16);
}

// tokens [32768,1024] fp32 -> Th, Tl bf16 row-major
__global__ __launch_bounds__(256) void split_tok(const float* __restrict__ T,
    u16* __restrict__ Th, u16* __restrict__ Tl) {
  size_t id = (size_t)blockIdx.x * 256 + threadIdx.x;   // 4M threads
  size_t base = id * 8;
  float4 v0 = *(const float4*)(T + base);
  float4 v1 = *(const float4*)(T + base + 4);
  float a[8] = {v0.x, v0.y, v0.z, v0.w, v1.x, v1.y, v1.z, v1.w};
  u16 h[8], l[8];
#pragma unroll
  for (int j = 0; j < 8; j++) split2(a[j], h[j], l[j]);
  *(uint4*)(Th + base) = *(uint4*)h;
  *(uint4*)(Tl + base) = *(uint4*)l;
}

// W [1024,N] fp32 -> Wh,Wl transposed [N,1024] bf16. Coalesced reads along n.
__global__ __launch_bounds__(256) void split_wT(const float* __restrict__ W,
    int N, u16* __restrict__ Wh, u16* __restrict__ Wl) {
  int id = blockIdx.x * 256 + threadIdx.x;   // N*128 threads
  int n = id & (N - 1);
  int k0 = (id / N) * 8;
  float a[8];
#pragma unroll
  for (int j = 0; j < 8; j++) a[j] = W[(size_t)(k0 + j) * N + n];
  u16 h[8], l[8];
#pragma unroll
  for (int j = 0; j < 8; j++) split2(a[j], h[j], l[j]);
  *(uint4*)(Wh + (size_t)n * 1024 + k0) = *(uint4*)h;
  *(uint4*)(Wl + (size_t)n * 1024 + k0) = *(uint4*)l;
}

__device__ __forceinline__ void gll16(const void* g, void* l) {
  __builtin_amdgcn_global_load_lds(
      (const __attribute__((address_space(1))) void*)g,
      (__attribute__((address_space(3))) void*)l, 16, 0, 0);
}

// ---------------------------------------------------------------------------
// bf16x3 MFMA GEMM: C = A*B, A=[32768,1024] (hi/lo), B^T=[N,1024] (hi/lo).
// mode 0: store fp16 C. mode 1: fp32 store of acc + H[b,cid] + bres.
// 128x128 tile, BK=32, 4 waves (2x2 of 64x64), 16x16x32 MFMA, 3 products.
// global_load_lds staging with swizzle baked into per-lane global addresses.
// ---------------------------------------------------------------------------
__global__ __launch_bounds__(256) void gemm_mfma(
    const u16* __restrict__ Ah, const u16* __restrict__ Al,
    const u16* __restrict__ Bh, const u16* __restrict__ Bl,
    void* __restrict__ Cout, int N, int NTN, int mode,
    const float* __restrict__ Hs, const int* __restrict__ cid,
    const float* __restrict__ bres)
{
  __shared__ u16 lds4[4][4096];   // Ah,Al,Bh,Bl tiles: 128 rows x 32 bf16
  const int tid = threadIdx.x;
  const int lane = tid & 63, w = tid >> 6;
  const int q = lane >> 4, fr = lane & 15;
  const int wr = w >> 1, wc = w & 1;
  // XCD swizzle: all n-tiles of an m-row stay on one XCD (L2 reuse of A)
  int bid = blockIdx.x;
  int idx = bid >> 3, x = bid & 7;
  const int n0 = (idx % NTN) * 128;
  const int m0 = (x * 32 + idx / NTN) * 128;

  const u16* src = (w == 0) ? Ah : (w == 1) ? Al : (w == 2) ? Bh : Bl;
  const int rowbase = (w < 2) ? m0 : n0;

  v4f acc[4][4];
#pragma unroll
  for (int i = 0; i < 4; i++)
#pragma unroll
    for (int j = 0; j < 4; j++) acc[i][j] = (v4f)0.f;

  for (int kt = 0; kt < 32; kt++) {
    const u16* sk = src + kt * 32;
#pragma unroll
    for (int j = 0; j < 8; j++) {            // stage 8KB per wave
      int lam = j * 64 + lane;
      int mi = lam >> 2;
      int qq = (lam & 3) ^ ((lam >> 3) & 3); // chunk swizzle (2-way max)
      gll16(sk + (size_t)(rowbase + mi) * 1024 + qq * 8, &lds4[w][j * 512]);
    }
    __syncthreads();                         // drains vmcnt before reads
    v8s bh[4], bl[4];
#pragma unroll
    for (int nt = 0; nt < 4; nt++) {
      int r = wc * 64 + nt * 16 + fr;
      int off = r * 32 + ((q ^ ((r >> 1) & 3)) << 3);
      bh[nt] = *(const v8s*)&lds4[2][off];
      bl[nt] = *(const v8s*)&lds4[3][off];
    }
#pragma unroll
    for (int mt = 0; mt < 4; mt++) {
      int r = wr * 64 + mt * 16 + fr;
      int off = r * 32 + ((q ^ ((r >> 1) & 3)) << 3);
      v8s ah = *(const v8s*)&lds4[0][off];
      v8s al = *(const v8s*)&lds4[1][off];
#pragma unroll
      for (int nt = 0; nt < 4; nt++) {
        acc[mt][nt] = __builtin_amdgcn_mfma_f32_16x16x32_bf16(ah, bh[nt], acc[mt][nt], 0, 0, 0);
        acc[mt][nt] = __builtin_amdgcn_mfma_f32_16x16x32_bf16(al, bh[nt], acc[mt][nt], 0, 0, 0);
        acc[mt][nt] = __builtin_amdgcn_mfma_f32_16x16x32_bf16(ah, bl[nt], acc[mt][nt], 0, 0, 0);
      }
    }
    __syncthreads();                         // compute done before re-stage
  }

  if (mode == 0) {
    __half* C = (__half*)Cout;
#pragma unroll
    for (int mt = 0; mt < 4; mt++)
#pragma unroll
      for (int r = 0; r < 4; r++) {
        int grow = m0 + wr * 64 + mt * 16 + q * 4 + r;
        __half* crow = C + (size_t)grow * N + n0 + wc * 64 + fr;
#pragma unroll
        for (int nt = 0; nt < 4; nt++)
          crow[nt * 16] = __float2half(acc[mt][nt][r]);
      }
  } else {
    float* C = (float*)Cout;
#pragma unroll
    for (int mt = 0; mt < 4; mt++)
#pragma unroll
      for (int r = 0; r < 4; r++) {
        int grow = m0 + wr * 64 + mt * 16 + q * 4 + r;
        int b = grow >> 12;
        int cc = cid[grow];
        const float* hrow = Hs + (size_t)((b << 12) + cc) * 1024 + n0 + wc * 64 + fr;
        const float* brow = bres + n0 + wc * 64 + fr;
        float* crow = C + (size_t)grow * 1024 + n0 + wc * 64 + fr;
#pragma unroll
        for (int nt = 0; nt < 4; nt++)
          crow[nt * 16] = acc[mt][nt][r] + hrow[nt * 16] + brow[nt * 16];
      }
  }
}

// ---------------------------------------------------------------------------
// probs from fp16 C1: one wave per position.
// ---------------------------------------------------------------------------
__global__ __launch_bounds__(256) void probs_half(const __half* __restrict__ C1,
    const float* __restrict__ skey, float* __restrict__ probs)
{
  int gt = blockIdx.x * 256 + threadIdx.x;
  int wid = gt >> 6, lane = threadIdx.x & 63;
  float qv[16], kv[16];
  {
    const __half2* p2 = (const __half2*)(C1 + (size_t)wid * 2048 + lane * 16);
#pragma unroll
    for (int j = 0; j < 8; j++) {
      float2 f = __half22float2(p2[j]); qv[2 * j] = f.x; qv[2 * j + 1] = f.y;
    }
  }
  if ((wid & 4095) == 0) {
#pragma unroll
    for (int j = 0; j < 16; j++) kv[j] = skey[lane * 16 + j];
  } else {
    const __half2* p2 = (const __half2*)(C1 + (size_t)(wid - 1) * 2048 + 1024 + lane * 16);
#pragma unroll
    for (int j = 0; j < 8; j++) {
      float2 f = __half22float2(p2[j]); kv[2 * j] = f.x; kv[2 * j + 1] = f.y;
    }
  }
  float dq = 0.f, nq = 0.f, nk = 0.f;
#pragma unroll
  for (int j = 0; j < 16; j++) {
    dq += qv[j] * kv[j]; nq += qv[j] * qv[j]; nk += kv[j] * kv[j];
  }
#pragma unroll
  for (int off = 32; off > 0; off >>= 1) {
    dq += __shfl_down(dq, off);
    nq += __shfl_down(nq, off);
    nk += __shfl_down(nk, off);
  }
  if (lane == 0)
    probs[wid] = 0.5f * (1.f - dq / fmaxf(sqrtf(nq) * sqrtf(nk), 1e-8f));
}

// ---------------------------------------------------------------------------
// flag compaction: positions with |cos| < 1e-4 -> flags list (count in cnt)
// flags/cnt alias the dead C1h region (C1h last read by probs_half).
// ---------------------------------------------------------------------------
__global__ void zero_cnt(int* __restrict__ cnt) {
  if (threadIdx.x == 0) *cnt = 0;
}

__global__ __launch_bounds__(256) void flag_kernel(
    const float* __restrict__ probs, int* __restrict__ flags,
    int* __restrict__ cnt)
{
  int gm = blockIdx.x * 256 + threadIdx.x;
  float cosv = 1.f - 2.f * probs[gm];
  if (fabsf(cosv) < 1e-4f) {
    int idx = atomicAdd(cnt, 1);
    if (idx < RCAP) flags[idx] = gm;
  }
}

// ---------------------------------------------------------------------------
// fp64 re-check v2: one block per flagged position.
// Token rows staged in LDS; Wqk read as coalesced float4 (thread t owns
// columns 4t..4t+3); 8 independent fp64 accumulator chains per thread.
// ---------------------------------------------------------------------------
__global__ __launch_bounds__(256) void recheck2(
    const float* __restrict__ tok, const float* __restrict__ Wqk,
    const float* __restrict__ sk, float* __restrict__ probs,
    const int* __restrict__ flags, const int* __restrict__ cnt)
{
  __shared__ float sq[1024], sp[1024];
  __shared__ double red[3][4];
  int nf = *cnt; if (nf > RCAP) nf = RCAP;
  int t = threadIdx.x;
  for (int fi = blockIdx.x; fi < nf; fi += gridDim.x) {
    int gm = flags[fi];
    int l = gm & 4095;
    const float* trow = tok + (size_t)gm * 1024;
    for (int j = t; j < 1024; j += 256) {
      sq[j] = trow[j];
      sp[j] = l ? trow[j - 1024] : 0.f;   // prev token row (guarded: no OOB at l==0)
    }
    __syncthreads();
    double qe0 = 0, qe1 = 0, qe2 = 0, qe3 = 0;
    double ke0 = 0, ke1 = 0, ke2 = 0, ke3 = 0;
    const float4* wq = (const float4*)Wqk + t;            // cols 4t..4t+3 of q-half
    const float4* wk = (const float4*)(Wqk + 1024) + t;   // cols 4t..4t+3 of k-half
#pragma unroll 4
    for (int d = 0; d < 1024; d++) {
      double td = (double)sq[d];
      double pd = (double)sp[d];
      float4 a = wq[(size_t)d * 512];     // Wqk[d][4t..4t+3]
      float4 b = wk[(size_t)d * 512];     // Wqk[d][1024+4t..]
      qe0 += td * (double)a.x; qe1 += td * (double)a.y;
      qe2 += td * (double)a.z; qe3 += td * (double)a.w;
      ke0 += pd * (double)b.x; ke1 += pd * (double)b.y;
      ke2 += pd * (double)b.z; ke3 += pd * (double)b.w;
    }
    if (l == 0) {
      float4 s4 = *((const float4*)sk + t);
      ke0 = (double)s4.x; ke1 = (double)s4.y;
      ke2 = (double)s4.z; ke3 = (double)s4.w;
    }
    double dq = qe0 * ke0 + qe1 * ke1 + qe2 * ke2 + qe3 * ke3;
    double nq = qe0 * qe0 + qe1 * qe1 + qe2 * qe2 + qe3 * qe3;
    double nk = ke0 * ke0 + ke1 * ke1 + ke2 * ke2 + ke3 * ke3;
#pragma unroll
    for (int off = 32; off > 0; off >>= 1) {
      dq += __shfl_down(dq, off);
      nq += __shfl_down(nq, off);
      nk += __shfl_down(nk, off);
    }
    int w = t >> 6;
    if ((t & 63) == 0) { red[0][w] = dq; red[1][w] = nq; red[2][w] = nk; }
    __syncthreads();
    if (t == 0) {
      double DQ = red[0][0] + red[0][1] + red[0][2] + red[0][3];
      double NQ = red[1][0] + red[1][1] + red[1][2] + red[1][3];
      double NK = red[2][0] + red[2][1] + red[2][2] + red[2][3];
      double den = sqrt(NQ) * sqrt(NK);
      if (den < 1e-8) den = 1e-8;
      probs[gm] = (float)(0.5 * (1.0 - DQ / den));
    }
    __syncthreads();   // sq/sp/red reused next iteration
  }
}

// ---------------------------------------------------------------------------
// meta: boundaries, chunk ids, compaction, num_chunks, aux per batch
// ---------------------------------------------------------------------------
__global__ __launch_bounds__(256) void meta_kernel(
    const float* __restrict__ probs, int* __restrict__ cid,
    int* __restrict__ pos, float* __restrict__ cprob,
    int* __restrict__ numC, float* __restrict__ auxv)
{
  __shared__ int   sc[256];
  __shared__ float psh[256];
  int b = blockIdx.x, t = threadIdx.x;
  const float* pr = probs + b * 4096;
  int base = t * 16;
  float pv[16]; int loc[16]; bool bd[16];
  int cnt = 0; float ps = 0.f;
#pragma unroll
  for (int i = 0; i < 16; i++) {
    float p = pr[base + i];
    pv[i] = p; ps += p;
    bool bb = (base + i == 0) || (p > 0.5f);
    bd[i] = bb; cnt += bb ? 1 : 0; loc[i] = cnt;
  }
  sc[t] = cnt; psh[t] = ps;
  __syncthreads();
  for (int off = 1; off < 256; off <<= 1) {
    int add = (t >= off) ? sc[t - off] : 0;
    __syncthreads();
    sc[t] += add;
    __syncthreads();
  }
  int excl = sc[t] - cnt;
#pragma unroll
  for (int i = 0; i < 16; i++) {
    int c = excl + loc[i] - 1;
    cid[b * 4096 + base + i] = c;
    if (bd[i]) { pos[b * 4096 + c] = base + i; cprob[b * 4096 + c] = pv[i]; }
  }
  int total = sc[255];
  for (int off = 128; off > 0; off >>= 1) {
    if (t < off) psh[t] += psh[t + off];
    __syncthreads();
  }
  if (t == 0) {
    numC[b] = total;
    float F = (float)total / 4096.f;
    float G = psh[0] / 4096.f;
    auxv[b] = 1.2f * (5.f * F * G + (1.f - F) * (1.f - G));
  }
}

__global__ void aux_final(const float* __restrict__ auxv, float* __restrict__ out2)
{
  if (threadIdx.x == 0) {
    float s = 0.f;
    for (int i = 0; i < 8; i++) s += auxv[i];
    out2[0] = s * (0.03f / 8.f);
  }
}

__global__ __launch_bounds__(256) void down_kernel(
    const float* __restrict__ tok, const int* __restrict__ pos,
    const float* __restrict__ cprob, const int* __restrict__ numC,
    float* __restrict__ out0)
{
  int blk = blockIdx.x;
  int b = blk >> 12, slot = blk & 4095;
  float4 v = make_float4(0.f, 0.f, 0.f, 0.f);
  if (slot < numC[b]) {
    int l = pos[blk];
    float p = cprob[blk];
    float4 tv = *(const float4*)(tok + (size_t)((b << 12) + l) * 1024 + threadIdx.x * 4);
    v = make_float4(p * tv.x, p * tv.y, p * tv.z, p * tv.w);
  }
  *(float4*)(out0 + (size_t)blk * 1024 + threadIdx.x * 4) = v;
}

// Segmented gated scan, 64-step warm-up (gates < 0.5 => error < 2^-64)
__global__ __launch_bounds__(256) void scanH_kernel(
    const float* __restrict__ out0, const float* __restrict__ cprob,
    const int* __restrict__ numC, float* __restrict__ H)
{
  int seg = blockIdx.x, b = blockIdx.y;
  int nc = numC[b];
  int cs = seg << 8;
  if (cs >= nc) return;
  int ce = min(cs + 256, nc);
  int c0 = (seg == 0) ? 0 : cs - 64;
  int off = threadIdx.x * 4;
  float hx = 0.f, hy = 0.f, hz = 0.f, hw = 0.f;
  int c = c0;
  for (; c < cs; c++) {
    float g = 1.f - cprob[(b << 12) + c];
    float4 xv = *(const float4*)(out0 + (size_t)((b << 12) + c) * 1024 + off);
    hx = fmaf(g, hx, xv.x); hy = fmaf(g, hy, xv.y);
    hz = fmaf(g, hz, xv.z); hw = fmaf(g, hw, xv.w);
  }
  for (; c < ce; c++) {
    float g = 1.f - cprob[(b << 12) + c];
    float4 xv = *(const float4*)(out0 + (size_t)((b << 12) + c) * 1024 + off);
    hx = fmaf(g, hx, xv.x); hy = fmaf(g, hy, xv.y);
    hz = fmaf(g, hz, xv.z); hw = fmaf(g, hw, xv.w);
    *(float4*)(H + (size_t)((b << 12) + c) * 1024 + off) = make_float4(hx, hy, hz, hw);
  }
}

// ---------------------------------------------------------------------------
extern "C" void kernel_launch(void* const* d_in, const int* in_sizes, int n_in,
                              void* d_out, int out_size, void* d_ws, size_t ws_size,
                              hipStream_t stream)
{
  const float* tokens = (const float*)d_in[0];
  const float* Wqk    = (const float*)d_in[1];
  const float* sk     = (const float*)d_in[2];
  const float* Wres   = (const float*)d_in[3];
  const float* bres   = (const float*)d_in[4];

  float* out0 = (float*)d_out;
  float* out1 = out0 + (size_t)M_ * D_;
  float* out2 = out1 + (size_t)M_ * D_;

  char* ws = (char*)d_ws;
  __half* C1h  = (__half*)ws;                          // [32768,2048] fp16 = 134MB
  float*  Hbuf = (float*)ws;                           // aliases C1h (dead after probs)
  int*   rflags = (int*)ws;                            // aliases C1h too (dead after probs)
  int*   rcnt   = (int*)(ws + (size_t)RCAP * 4);
  u16* Th = (u16*)(ws + 134217728ull);                 // 67MB
  u16* Tl = (u16*)(ws + 201326592ull);                 // 67MB
  u16* Wh = (u16*)(ws + 268435456ull);                 // 4MB (shared qk/res)
  u16* Wl = (u16*)(ws + 272629760ull);                 // 4MB
  float* probs = (float*)(ws + 276824064ull);
  int*   cidp  = (int*)(ws + 276955136ull);
  int*   posp  = (int*)(ws + 277086208ull);
  float* cprob = (float*)(ws + 277217280ull);
  int*   numC  = (int*)(ws + 277348352ull);
  float* auxv  = (float*)(ws + 277348416ull);

  // 1. bf16 hi/lo splits
  split_tok<<<16384, 256, 0, stream>>>(tokens, Th, Tl);
  split_wT<<<1024, 256, 0, stream>>>(Wqk, 2048, Wh, Wl);
  // 2. qk projection: bf16x3 MFMA -> fp16 C1
  gemm_mfma<<<4096, 256, 0, stream>>>(Th, Tl, Wh, Wl, C1h, 2048, 16, 0,
                                      nullptr, nullptr, nullptr);
  // 3. cosine -> probs
  probs_half<<<8192, 256, 0, stream>>>(C1h, sk, probs);
  // 4. fp64 re-check near threshold: flag-compact, then 1 block / position.
  //    (flags/cnt live in the C1h region, which is dead after probs_half.)
  zero_cnt<<<1, 64, 0, stream>>>(rcnt);
  flag_kernel<<<128, 256, 0, stream>>>(probs, rflags, rcnt);
  recheck2<<<256, 256, 0, stream>>>(tokens, Wqk, sk, probs, rflags, rcnt);
  // 5. boundaries / chunk ids / compaction / aux
  meta_kernel<<<8, 256, 0, stream>>>(probs, cidp, posp, cprob, numC, auxv);
  aux_final<<<1, 64, 0, stream>>>(auxv, out2);
  // 6. downsampled
  down_kernel<<<M_, 256, 0, stream>>>(tokens, posp, cprob, numC, out0);
  // 7. gated scan -> H (overwrites C1h region; flags dead by now)
  scanH_kernel<<<dim3(16, 8), 256, 0, stream>>>(out0, cprob, numC, Hbuf);
  // 8. res splits (reuse W buffers — C1h already consumed)
  split_wT<<<512, 256, 0, stream>>>(Wres, 1024, Wh, Wl);
  // 9. ups = tokens@Wres + H[cid] + bres (bf16x3 MFMA, fused epilogue)
  gemm_mfma<<<2048, 256, 0, stream>>>(Th, Tl, Wh, Wl, out1, 1024, 8, 1,
                                      Hbuf, cidp, bres);
}

// Round 2
// 992.109 us; speedup vs baseline: 2.6389x; 1.4231x over previous
//
#include <hip/hip_runtime.h>
#include <hip/hip_fp16.h>
#include <cmath>

typedef unsigned short u16;
typedef _Float16 halfT;
typedef halfT v8h __attribute__((ext_vector_type(8)));
typedef float v4f __attribute__((ext_vector_type(4)));

#define B_   8
#define L_   4096
#define D_   1024
#define M_   32768
#define RCAP 8192

// ---------------------------------------------------------------------------
// tokens [32768,1024] fp32 -> fp16 row-major
// ---------------------------------------------------------------------------
__global__ __launch_bounds__(256) void split_tok(const float* __restrict__ T,
    u16* __restrict__ Tf) {
  size_t id = (size_t)blockIdx.x * 256 + threadIdx.x;   // 4M threads
  size_t base = id * 8;
  float4 v0 = *(const float4*)(T + base);
  float4 v1 = *(const float4*)(T + base + 4);
  float a[8] = {v0.x, v0.y, v0.z, v0.w, v1.x, v1.y, v1.z, v1.w};
  u16 h[8];
#pragma unroll
  for (int j = 0; j < 8; j++) h[j] = __half_as_ushort(__float2half(a[j]));
  *(uint4*)(Tf + base) = *(uint4*)h;
}

// W [1024,N] fp32 -> fp16 transposed [N,1024]. Coalesced reads along n.
__global__ __launch_bounds__(256) void split_wT(const float* __restrict__ W,
    int N, u16* __restrict__ Wf) {
  int id = blockIdx.x * 256 + threadIdx.x;   // N*128 threads
  int n = id & (N - 1);
  int k0 = (id / N) * 8;
  u16 h[8];
#pragma unroll
  for (int j = 0; j < 8; j++)
    h[j] = __half_as_ushort(__float2half(W[(size_t)(k0 + j) * N + n]));
  *(uint4*)(Wf + (size_t)n * 1024 + k0) = *(uint4*)h;
}

__device__ __forceinline__ void gll16(const void* g, void* l) {
  __builtin_amdgcn_global_load_lds(
      (const __attribute__((address_space(1))) void*)g,
      (__attribute__((address_space(3))) void*)l, 16, 0, 0);
}

// ---------------------------------------------------------------------------
// fp16 MFMA GEMM: C = A*B, A=[32768,1024] fp16, B^T=[N,1024] fp16.
// mode 0: store fp16 C. mode 1: fp32 store of acc + H[b,cid] + bres.
// 128x128 tile, BK=32, 4 waves (2x2 of 64x64), 16x16x32 f16 MFMA.
// global_load_lds staging with swizzle baked into per-lane global addresses.
// Waves 0,1 stage A rows [0,64)/[64,128); waves 2,3 stage B likewise.
// ---------------------------------------------------------------------------
__global__ __launch_bounds__(256) void gemm_f16(
    const u16* __restrict__ Af, const u16* __restrict__ Bf,
    void* __restrict__ Cout, int N, int NTN, int mode,
    const float* __restrict__ Hs, const int* __restrict__ cid,
    const float* __restrict__ bres)
{
  __shared__ u16 ldsA[4096], ldsB[4096];   // 128 rows x 32 fp16 each
  const int tid = threadIdx.x;
  const int lane = tid & 63, w = tid >> 6;
  const int q = lane >> 4, fr = lane & 15;
  const int wr = w >> 1, wc = w & 1;
  // XCD swizzle: all n-tiles of an m-row stay on one XCD (L2 reuse of A)
  int bid = blockIdx.x;
  int idx = bid >> 3, x = bid & 7;
  const int n0 = (idx % NTN) * 128;
  const int m0 = (x * 32 + idx / NTN) * 128;

  const u16* src = (w < 2) ? Af : Bf;
  const int rowbase = ((w < 2) ? m0 : n0) + (w & 1) * 64;
  u16* dst = ((w < 2) ? ldsA : ldsB) + (w & 1) * 2048;

  v4f acc[4][4];
#pragma unroll
  for (int i = 0; i < 4; i++)
#pragma unroll
    for (int j = 0; j < 4; j++) acc[i][j] = (v4f)0.f;

  for (int kt = 0; kt < 32; kt++) {
    const u16* sk = src + kt * 32;
#pragma unroll
    for (int j = 0; j < 4; j++) {            // stage 4KB per wave
      int lam = j * 64 + lane;
      int mi = lam >> 2;
      int qq = (lam & 3) ^ ((lam >> 3) & 3); // chunk swizzle (2-way max)
      gll16(sk + (size_t)(rowbase + mi) * 1024 + qq * 8, dst + j * 512);
    }
    __syncthreads();                         // drains vmcnt before reads
    v8h bh[4];
#pragma unroll
    for (int nt = 0; nt < 4; nt++) {
      int r = wc * 64 + nt * 16 + fr;
      int off = r * 32 + ((q ^ ((r >> 1) & 3)) << 3);
      bh[nt] = *(const v8h*)&ldsB[off];
    }
#pragma unroll
    for (int mt = 0; mt < 4; mt++) {
      int r = wr * 64 + mt * 16 + fr;
      int off = r * 32 + ((q ^ ((r >> 1) & 3)) << 3);
      v8h ah = *(const v8h*)&ldsA[off];
#pragma unroll
      for (int nt = 0; nt < 4; nt++)
        acc[mt][nt] = __builtin_amdgcn_mfma_f32_16x16x32_f16(ah, bh[nt], acc[mt][nt], 0, 0, 0);
    }
    __syncthreads();                         // compute done before re-stage
  }

  if (mode == 0) {
    __half* C = (__half*)Cout;
#pragma unroll
    for (int mt = 0; mt < 4; mt++)
#pragma unroll
      for (int r = 0; r < 4; r++) {
        int grow = m0 + wr * 64 + mt * 16 + q * 4 + r;
        __half* crow = C + (size_t)grow * N + n0 + wc * 64 + fr;
#pragma unroll
        for (int nt = 0; nt < 4; nt++)
          crow[nt * 16] = __float2half(acc[mt][nt][r]);
      }
  } else {
    float* C = (float*)Cout;
#pragma unroll
    for (int mt = 0; mt < 4; mt++)
#pragma unroll
      for (int r = 0; r < 4; r++) {
        int grow = m0 + wr * 64 + mt * 16 + q * 4 + r;
        int b = grow >> 12;
        int cc = cid[grow];
        const float* hrow = Hs + (size_t)((b << 12) + cc) * 1024 + n0 + wc * 64 + fr;
        const float* brow = bres + n0 + wc * 64 + fr;
        float* crow = C + (size_t)grow * 1024 + n0 + wc * 64 + fr;
#pragma unroll
        for (int nt = 0; nt < 4; nt++)
          crow[nt * 16] = acc[mt][nt][r] + hrow[nt * 16] + brow[nt * 16];
      }
  }
}

// ---------------------------------------------------------------------------
// probs from fp16 C1: one wave per position.
// ---------------------------------------------------------------------------
__global__ __launch_bounds__(256) void probs_half(const __half* __restrict__ C1,
    const float* __restrict__ skey, float* __restrict__ probs)
{
  int gt = blockIdx.x * 256 + threadIdx.x;
  int wid = gt >> 6, lane = threadIdx.x & 63;
  float qv[16], kv[16];
  {
    const __half2* p2 = (const __half2*)(C1 + (size_t)wid * 2048 + lane * 16);
#pragma unroll
    for (int j = 0; j < 8; j++) {
      float2 f = __half22float2(p2[j]); qv[2 * j] = f.x; qv[2 * j + 1] = f.y;
    }
  }
  if ((wid & 4095) == 0) {
#pragma unroll
    for (int j = 0; j < 16; j++) kv[j] = skey[lane * 16 + j];
  } else {
    const __half2* p2 = (const __half2*)(C1 + (size_t)(wid - 1) * 2048 + 1024 + lane * 16);
#pragma unroll
    for (int j = 0; j < 8; j++) {
      float2 f = __half22float2(p2[j]); kv[2 * j] = f.x; kv[2 * j + 1] = f.y;
    }
  }
  float dq = 0.f, nq = 0.f, nk = 0.f;
#pragma unroll
  for (int j = 0; j < 16; j++) {
    dq += qv[j] * kv[j]; nq += qv[j] * qv[j]; nk += kv[j] * kv[j];
  }
#pragma unroll
  for (int off = 32; off > 0; off >>= 1) {
    dq += __shfl_down(dq, off);
    nq += __shfl_down(nq, off);
    nk += __shfl_down(nk, off);
  }
  if (lane == 0)
    probs[wid] = 0.5f * (1.f - dq / fmaxf(sqrtf(nq) * sqrtf(nk), 1e-8f));
}

// ---------------------------------------------------------------------------
// flag compaction: positions with |cos| < 2.5e-4 -> flags list (count in cnt)
// flags/cnt alias the dead C1h region (C1h last read by probs_half).
// Band widened vs bf16x3 version: fp16x1 GEMM has cos error std ~2-3e-5,
// so 2.5e-4 is ~11 sigma against boundary flips.
// ---------------------------------------------------------------------------
__global__ void zero_cnt(int* __restrict__ cnt) {
  if (threadIdx.x == 0) *cnt = 0;
}

__global__ __launch_bounds__(256) void flag_kernel(
    const float* __restrict__ probs, int* __restrict__ flags,
    int* __restrict__ cnt)
{
  int gm = blockIdx.x * 256 + threadIdx.x;
  float cosv = 1.f - 2.f * probs[gm];
  if (fabsf(cosv) < 2.5e-4f) {
    int idx = atomicAdd(cnt, 1);
    if (idx < RCAP) flags[idx] = gm;
  }
}

// ---------------------------------------------------------------------------
// fp64 re-check: one block per flagged position.
// Token rows staged in LDS; Wqk read as coalesced float4 (thread t owns
// columns 4t..4t+3); 8 independent fp64 accumulator chains per thread.
// ---------------------------------------------------------------------------
__global__ __launch_bounds__(256) void recheck2(
    const float* __restrict__ tok, const float* __restrict__ Wqk,
    const float* __restrict__ sk, float* __restrict__ probs,
    const int* __restrict__ flags, const int* __restrict__ cnt)
{
  __shared__ float sq[1024], sp[1024];
  __shared__ double red[3][4];
  int nf = *cnt; if (nf > RCAP) nf = RCAP;
  int t = threadIdx.x;
  for (int fi = blockIdx.x; fi < nf; fi += gridDim.x) {
    int gm = flags[fi];
    int l = gm & 4095;
    const float* trow = tok + (size_t)gm * 1024;
    for (int j = t; j < 1024; j += 256) {
      sq[j] = trow[j];
      sp[j] = l ? trow[j - 1024] : 0.f;   // prev token row (guarded: no OOB at l==0)
    }
    __syncthreads();
    double qe0 = 0, qe1 = 0, qe2 = 0, qe3 = 0;
    double ke0 = 0, ke1 = 0, ke2 = 0, ke3 = 0;
    const float4* wq = (const float4*)Wqk + t;            // cols 4t..4t+3 of q-half
    const float4* wk = (const float4*)(Wqk + 1024) + t;   // cols 4t..4t+3 of k-half
#pragma unroll 4
    for (int d = 0; d < 1024; d++) {
      double td = (double)sq[d];
      double pd = (double)sp[d];
      float4 a = wq[(size_t)d * 512];     // Wqk[d][4t..4t+3]
      float4 b = wk[(size_t)d * 512];     // Wqk[d][1024+4t..]
      qe0 += td * (double)a.x; qe1 += td * (double)a.y;
      qe2 += td * (double)a.z; qe3 += td * (double)a.w;
      ke0 += pd * (double)b.x; ke1 += pd * (double)b.y;
      ke2 += pd * (double)b.z; ke3 += pd * (double)b.w;
    }
    if (l == 0) {
      float4 s4 = *((const float4*)sk + t);
      ke0 = (double)s4.x; ke1 = (double)s4.y;
      ke2 = (double)s4.z; ke3 = (double)s4.w;
    }
    double dq = qe0 * ke0 + qe1 * ke1 + qe2 * ke2 + qe3 * ke3;
    double nq = qe0 * qe0 + qe1 * qe1 + qe2 * qe2 + qe3 * qe3;
    double nk = ke0 * ke0 + ke1 * ke1 + ke2 * ke2 + ke3 * ke3;
#pragma unroll
    for (int off = 32; off > 0; off >>= 1) {
      dq += __shfl_down(dq, off);
      nq += __shfl_down(nq, off);
      nk += __shfl_down(nk, off);
    }
    int w = t >> 6;
    if ((t & 63) == 0) { red[0][w] = dq; red[1][w] = nq; red[2][w] = nk; }
    __syncthreads();
    if (t == 0) {
      double DQ = red[0][0] + red[0][1] + red[0][2] + red[0][3];
      double NQ = red[1][0] + red[1][1] + red[1][2] + red[1][3];
      double NK = red[2][0] + red[2][1] + red[2][2] + red[2][3];
      double den = sqrt(NQ) * sqrt(NK);
      if (den < 1e-8) den = 1e-8;
      probs[gm] = (float)(0.5 * (1.0 - DQ / den));
    }
    __syncthreads();   // sq/sp/red reused next iteration
  }
}

// ---------------------------------------------------------------------------
// meta: boundaries, chunk ids, compaction, num_chunks, aux per batch
// ---------------------------------------------------------------------------
__global__ __launch_bounds__(256) void meta_kernel(
    const float* __restrict__ probs, int* __restrict__ cid,
    int* __restrict__ pos, float* __restrict__ cprob,
    int* __restrict__ numC, float* __restrict__ auxv)
{
  __shared__ int   sc[256];
  __shared__ float psh[256];
  int b = blockIdx.x, t = threadIdx.x;
  const float* pr = probs + b * 4096;
  int base = t * 16;
  float pv[16]; int loc[16]; bool bd[16];
  int cnt = 0; float ps = 0.f;
#pragma unroll
  for (int i = 0; i < 16; i++) {
    float p = pr[base + i];
    pv[i] = p; ps += p;
    bool bb = (base + i == 0) || (p > 0.5f);
    bd[i] = bb; cnt += bb ? 1 : 0; loc[i] = cnt;
  }
  sc[t] = cnt; psh[t] = ps;
  __syncthreads();
  for (int off = 1; off < 256; off <<= 1) {
    int add = (t >= off) ? sc[t - off] : 0;
    __syncthreads();
    sc[t] += add;
    __syncthreads();
  }
  int excl = sc[t] - cnt;
#pragma unroll
  for (int i = 0; i < 16; i++) {
    int c = excl + loc[i] - 1;
    cid[b * 4096 + base + i] = c;
    if (bd[i]) { pos[b * 4096 + c] = base + i; cprob[b * 4096 + c] = pv[i]; }
  }
  int total = sc[255];
  for (int off = 128; off > 0; off >>= 1) {
    if (t < off) psh[t] += psh[t + off];
    __syncthreads();
  }
  if (t == 0) {
    numC[b] = total;
    float F = (float)total / 4096.f;
    float G = psh[0] / 4096.f;
    auxv[b] = 1.2f * (5.f * F * G + (1.f - F) * (1.f - G));
  }
}

__global__ void aux_final(const float* __restrict__ auxv, float* __restrict__ out2)
{
  if (threadIdx.x == 0) {
    float s = 0.f;
    for (int i = 0; i < 8; i++) s += auxv[i];
    out2[0] = s * (0.03f / 8.f);
  }
}

__global__ __launch_bounds__(256) void down_kernel(
    const float* __restrict__ tok, const int* __restrict__ pos,
    const float* __restrict__ cprob, const int* __restrict__ numC,
    float* __restrict__ out0)
{
  int blk = blockIdx.x;
  int b = blk >> 12, slot = blk & 4095;
  float4 v = make_float4(0.f, 0.f, 0.f, 0.f);
  if (slot < numC[b]) {
    int l = pos[blk];
    float p = cprob[blk];
    float4 tv = *(const float4*)(tok + (size_t)((b << 12) + l) * 1024 + threadIdx.x * 4);
    v = make_float4(p * tv.x, p * tv.y, p * tv.z, p * tv.w);
  }
  *(float4*)(out0 + (size_t)blk * 1024 + threadIdx.x * 4) = v;
}

// Segmented gated scan, 64-step warm-up (gates < 0.5 => error < 2^-64)
__global__ __launch_bounds__(256) void scanH_kernel(
    const float* __restrict__ out0, const float* __restrict__ cprob,
    const int* __restrict__ numC, float* __restrict__ H)
{
  int seg = blockIdx.x, b = blockIdx.y;
  int nc = numC[b];
  int cs = seg << 8;
  if (cs >= nc) return;
  int ce = min(cs + 256, nc);
  int c0 = (seg == 0) ? 0 : cs - 64;
  int off = threadIdx.x * 4;
  float hx = 0.f, hy = 0.f, hz = 0.f, hw = 0.f;
  int c = c0;
  for (; c < cs; c++) {
    float g = 1.f - cprob[(b << 12) + c];
    float4 xv = *(const float4*)(out0 + (size_t)((b << 12) + c) * 1024 + off);
    hx = fmaf(g, hx, xv.x); hy = fmaf(g, hy, xv.y);
    hz = fmaf(g, hz, xv.z); hw = fmaf(g, hw, xv.w);
  }
  for (; c < ce; c++) {
    float g = 1.f - cprob[(b << 12) + c];
    float4 xv = *(const float4*)(out0 + (size_t)((b << 12) + c) * 1024 + off);
    hx = fmaf(g, hx, xv.x); hy = fmaf(g, hy, xv.y);
    hz = fmaf(g, hz, xv.z); hw = fmaf(g, hw, xv.w);
    *(float4*)(H + (size_t)((b << 12) + c) * 1024 + off) = make_float4(hx, hy, hz, hw);
  }
}

// ---------------------------------------------------------------------------
extern "C" void kernel_launch(void* const* d_in, const int* in_sizes, int n_in,
                              void* d_out, int out_size, void* d_ws, size_t ws_size,
                              hipStream_t stream)
{
  const float* tokens = (const float*)d_in[0];
  const float* Wqk    = (const float*)d_in[1];
  const float* sk     = (const float*)d_in[2];
  const float* Wres   = (const float*)d_in[3];
  const float* bres   = (const float*)d_in[4];

  float* out0 = (float*)d_out;
  float* out1 = out0 + (size_t)M_ * D_;
  float* out2 = out1 + (size_t)M_ * D_;

  char* ws = (char*)d_ws;
  __half* C1h  = (__half*)ws;                          // [32768,2048] fp16 = 134MB
  float*  Hbuf = (float*)ws;                           // aliases C1h (dead after probs)
  int*   rflags = (int*)ws;                            // aliases C1h too (dead after probs)
  int*   rcnt   = (int*)(ws + (size_t)RCAP * 4);
  u16* Tf = (u16*)(ws + 134217728ull);                 // 67MB fp16 tokens
  u16* Wf = (u16*)(ws + 268435456ull);                 // 4MB fp16 W^T (shared qk/res)
  float* probs = (float*)(ws + 276824064ull);
  int*   cidp  = (int*)(ws + 276955136ull);
  int*   posp  = (int*)(ws + 277086208ull);
  float* cprob = (float*)(ws + 277217280ull);
  int*   numC  = (int*)(ws + 277348352ull);
  float* auxv  = (float*)(ws + 277348416ull);

  // 1. fp16 casts
  split_tok<<<16384, 256, 0, stream>>>(tokens, Tf);
  split_wT<<<1024, 256, 0, stream>>>(Wqk, 2048, Wf);
  // 2. qk projection: fp16 MFMA -> fp16 C1
  gemm_f16<<<4096, 256, 0, stream>>>(Tf, Wf, C1h, 2048, 16, 0,
                                     nullptr, nullptr, nullptr);
  // 3. cosine -> probs
  probs_half<<<8192, 256, 0, stream>>>(C1h, sk, probs);
  // 4. fp64 re-check near threshold: flag-compact, then 1 block / position.
  //    (flags/cnt live in the C1h region, which is dead after probs_half.)
  zero_cnt<<<1, 64, 0, stream>>>(rcnt);
  flag_kernel<<<128, 256, 0, stream>>>(probs, rflags, rcnt);
  recheck2<<<512, 256, 0, stream>>>(tokens, Wqk, sk, probs, rflags, rcnt);
  // 5. boundaries / chunk ids / compaction / aux
  meta_kernel<<<8, 256, 0, stream>>>(probs, cidp, posp, cprob, numC, auxv);
  aux_final<<<1, 64, 0, stream>>>(auxv, out2);
  // 6. downsampled
  down_kernel<<<M_, 256, 0, stream>>>(tokens, posp, cprob, numC, out0);
  // 7. gated scan -> H (overwrites C1h region; flags dead by now)
  scanH_kernel<<<dim3(16, 8), 256, 0, stream>>>(out0, cprob, numC, Hbuf);
  // 8. res weights cast (reuse Wf — qk GEMM already consumed it)
  split_wT<<<512, 256, 0, stream>>>(Wres, 1024, Wf);
  // 9. ups = tokens@Wres + H[cid] + bres (fp16 MFMA, fused epilogue)
  gemm_f16<<<2048, 256, 0, stream>>>(Tf, Wf, out1, 1024, 8, 1,
                                     Hbuf, cidp, bres);
}

// Round 3
// 986.057 us; speedup vs baseline: 2.6551x; 1.0061x over previous
//
#include <hip/hip_runtime.h>
#include <hip/hip_fp16.h>
#include <cmath>

typedef unsigned short u16;
typedef _Float16 halfT;
typedef halfT v8h __attribute__((ext_vector_type(8)));
typedef float v4f __attribute__((ext_vector_type(4)));

#define B_   8
#define L_   4096
#define D_   1024
#define M_   32768
#define RCAP 8192

// ---------------------------------------------------------------------------
// tokens [32768,1024] fp32 -> fp16 row-major
// ---------------------------------------------------------------------------
__global__ __launch_bounds__(256) void split_tok(const float* __restrict__ T,
    u16* __restrict__ Tf) {
  size_t id = (size_t)blockIdx.x * 256 + threadIdx.x;   // 4M threads
  size_t base = id * 8;
  float4 v0 = *(const float4*)(T + base);
  float4 v1 = *(const float4*)(T + base + 4);
  float a[8] = {v0.x, v0.y, v0.z, v0.w, v1.x, v1.y, v1.z, v1.w};
  u16 h[8];
#pragma unroll
  for (int j = 0; j < 8; j++) h[j] = __half_as_ushort(__float2half(a[j]));
  *(uint4*)(Tf + base) = *(uint4*)h;
}

// W [1024,N] fp32 -> fp16 transposed [N,1024]. Coalesced reads along n.
__global__ __launch_bounds__(256) void split_wT(const float* __restrict__ W,
    int N, u16* __restrict__ Wf) {
  int id = blockIdx.x * 256 + threadIdx.x;   // N*128 threads
  int n = id & (N - 1);
  int k0 = (id / N) * 8;
  u16 h[8];
#pragma unroll
  for (int j = 0; j < 8; j++)
    h[j] = __half_as_ushort(__float2half(W[(size_t)(k0 + j) * N + n]));
  *(uint4*)(Wf + (size_t)n * 1024 + k0) = *(uint4*)h;
}

__device__ __forceinline__ void gll16(const void* g, void* l) {
  __builtin_amdgcn_global_load_lds(
      (const __attribute__((address_space(1))) void*)g,
      (__attribute__((address_space(3))) void*)l, 16, 0, 0);
}

// ---------------------------------------------------------------------------
// fp16 MFMA GEMM: C = A*B, A=[32768,1024] fp16, B^T=[N,1024] fp16.
// mode 0: store fp16 C. mode 1: fp32 store of acc + H[b,cid] + bres.
// 128x128 tile, BK=64 (32 MFMA per barrier-pair), 4 waves (2x2 of 64x64),
// 16x16x32 f16 MFMA. global_load_lds staging, linear LDS dest, chunk swizzle
// baked into per-lane global source addresses (rule: both-sides-or-neither).
// Rows are 128B (8 chunks of 16B); physical chunk c of row r holds logical
// chunk c^(r&7); reads use chunk ((q+4kk)^(r&7)) -> 2-way max conflict.
// ---------------------------------------------------------------------------
__global__ __launch_bounds__(256) void gemm_f16(
    const u16* __restrict__ Af, const u16* __restrict__ Bf,
    void* __restrict__ Cout, int N, int NTN, int mode,
    const float* __restrict__ Hs, const int* __restrict__ cid,
    const float* __restrict__ bres)
{
  __shared__ u16 ldsA[8192], ldsB[8192];   // 128 rows x 64 fp16 each (32KB)
  const int tid = threadIdx.x;
  const int lane = tid & 63, w = tid >> 6;
  const int q = lane >> 4, fr = lane & 15;
  const int wr = w >> 1, wc = w & 1;
  // XCD swizzle: all n-tiles of an m-row stay on one XCD (L2 reuse of A)
  int bid = blockIdx.x;
  int idx = bid >> 3, x = bid & 7;
  const int n0 = (idx % NTN) * 128;
  const int m0 = (x * 32 + idx / NTN) * 128;

  const u16* src = (w < 2) ? Af : Bf;
  const int rowbase = ((w < 2) ? m0 : n0) + (w & 1) * 64;
  u16* dst = ((w < 2) ? ldsA : ldsB) + (w & 1) * 4096;

  const int lhi = lane >> 3;                 // row-within-8 of this lane
  const int swz = (lane & 7) ^ lhi;          // pre-swizzled global chunk

  v4f acc[4][4];
#pragma unroll
  for (int i = 0; i < 4; i++)
#pragma unroll
    for (int j = 0; j < 4; j++) acc[i][j] = (v4f)0.f;

  for (int kt = 0; kt < 16; kt++) {
    const u16* sk = src + kt * 64;
#pragma unroll
    for (int j = 0; j < 8; j++) {            // stage 8KB per wave (64 rows)
      int mi = j * 8 + lhi;
      gll16(sk + (size_t)(rowbase + mi) * 1024 + swz * 8, dst + j * 512);
    }
    __syncthreads();                         // drains vmcnt before reads
    v8h bh[4][2];
#pragma unroll
    for (int nt = 0; nt < 4; nt++) {
      int r = wc * 64 + nt * 16 + fr;
#pragma unroll
      for (int kk = 0; kk < 2; kk++) {
        int off = r * 64 + (((q + 4 * kk) ^ (r & 7)) << 3);
        bh[nt][kk] = *(const v8h*)&ldsB[off];
      }
    }
#pragma unroll
    for (int mt = 0; mt < 4; mt++) {
      int r = wr * 64 + mt * 16 + fr;
      v8h ah0 = *(const v8h*)&ldsA[r * 64 + ((q ^ (r & 7)) << 3)];
      v8h ah1 = *(const v8h*)&ldsA[r * 64 + (((q + 4) ^ (r & 7)) << 3)];
#pragma unroll
      for (int nt = 0; nt < 4; nt++) {
        acc[mt][nt] = __builtin_amdgcn_mfma_f32_16x16x32_f16(ah0, bh[nt][0], acc[mt][nt], 0, 0, 0);
        acc[mt][nt] = __builtin_amdgcn_mfma_f32_16x16x32_f16(ah1, bh[nt][1], acc[mt][nt], 0, 0, 0);
      }
    }
    __syncthreads();                         // compute done before re-stage
  }

  if (mode == 0) {
    __half* C = (__half*)Cout;
#pragma unroll
    for (int mt = 0; mt < 4; mt++)
#pragma unroll
      for (int r = 0; r < 4; r++) {
        int grow = m0 + wr * 64 + mt * 16 + q * 4 + r;
        __half* crow = C + (size_t)grow * N + n0 + wc * 64 + fr;
#pragma unroll
        for (int nt = 0; nt < 4; nt++)
          crow[nt * 16] = __float2half(acc[mt][nt][r]);
      }
  } else {
    float* C = (float*)Cout;
#pragma unroll
    for (int mt = 0; mt < 4; mt++)
#pragma unroll
      for (int r = 0; r < 4; r++) {
        int grow = m0 + wr * 64 + mt * 16 + q * 4 + r;
        int b = grow >> 12;
        int cc = cid[grow];
        const float* hrow = Hs + (size_t)((b << 12) + cc) * 1024 + n0 + wc * 64 + fr;
        const float* brow = bres + n0 + wc * 64 + fr;
        float* crow = C + (size_t)grow * 1024 + n0 + wc * 64 + fr;
#pragma unroll
        for (int nt = 0; nt < 4; nt++)
          crow[nt * 16] = acc[mt][nt][r] + hrow[nt * 16] + brow[nt * 16];
      }
  }
}

// ---------------------------------------------------------------------------
// probs from fp16 C1: one wave per position. Fused near-threshold flagging
// (|cos| < 2.5e-4 -> flags list). flags live in out1 (scratch until the
// final GEMM overwrites it) -- NOT in C1h, which this kernel reads.
// ---------------------------------------------------------------------------
__global__ __launch_bounds__(256) void probs_half(const __half* __restrict__ C1,
    const float* __restrict__ skey, float* __restrict__ probs,
    int* __restrict__ flags, int* __restrict__ cnt)
{
  int gt = blockIdx.x * 256 + threadIdx.x;
  int wid = gt >> 6, lane = threadIdx.x & 63;
  float qv[16], kv[16];
  {
    const uint4* p4 = (const uint4*)(C1 + (size_t)wid * 2048 + lane * 16);
    uint4 u0 = p4[0], u1 = p4[1];
    unsigned uu[8] = {u0.x, u0.y, u0.z, u0.w, u1.x, u1.y, u1.z, u1.w};
#pragma unroll
    for (int j = 0; j < 8; j++) {
      float2 f = __half22float2(*(const __half2*)&uu[j]);
      qv[2 * j] = f.x; qv[2 * j + 1] = f.y;
    }
  }
  if ((wid & 4095) == 0) {
#pragma unroll
    for (int j = 0; j < 16; j++) kv[j] = skey[lane * 16 + j];
  } else {
    const uint4* p4 = (const uint4*)(C1 + (size_t)(wid - 1) * 2048 + 1024 + lane * 16);
    uint4 u0 = p4[0], u1 = p4[1];
    unsigned uu[8] = {u0.x, u0.y, u0.z, u0.w, u1.x, u1.y, u1.z, u1.w};
#pragma unroll
    for (int j = 0; j < 8; j++) {
      float2 f = __half22float2(*(const __half2*)&uu[j]);
      kv[2 * j] = f.x; kv[2 * j + 1] = f.y;
    }
  }
  float dq = 0.f, nq = 0.f, nk = 0.f;
#pragma unroll
  for (int j = 0; j < 16; j++) {
    dq += qv[j] * kv[j]; nq += qv[j] * qv[j]; nk += kv[j] * kv[j];
  }
#pragma unroll
  for (int off = 32; off > 0; off >>= 1) {
    dq += __shfl_down(dq, off);
    nq += __shfl_down(nq, off);
    nk += __shfl_down(nk, off);
  }
  if (lane == 0) {
    float cosv = dq / fmaxf(sqrtf(nq) * sqrtf(nk), 1e-8f);
    probs[wid] = 0.5f * (1.f - cosv);
    if (fabsf(cosv) < 2.5e-4f) {            // fp16x1 cos err std ~2-3e-5: 11 sigma
      int idx = atomicAdd(cnt, 1);
      if (idx < RCAP) flags[idx] = wid;
    }
  }
}

__global__ void zero_cnt(int* __restrict__ cnt) {
  if (threadIdx.x == 0) *cnt = 0;
}

// ---------------------------------------------------------------------------
// fp64 re-check: one block per flagged position.
// Token rows staged in LDS; Wqk read as coalesced float4 (thread t owns
// columns 4t..4t+3); 8 independent fp64 accumulator chains per thread.
// ---------------------------------------------------------------------------
__global__ __launch_bounds__(256) void recheck2(
    const float* __restrict__ tok, const float* __restrict__ Wqk,
    const float* __restrict__ sk, float* __restrict__ probs,
    const int* __restrict__ flags, const int* __restrict__ cnt)
{
  __shared__ float sq[1024], sp[1024];
  __shared__ double red[3][4];
  int nf = *cnt; if (nf > RCAP) nf = RCAP;
  int t = threadIdx.x;
  for (int fi = blockIdx.x; fi < nf; fi += gridDim.x) {
    int gm = flags[fi];
    int l = gm & 4095;
    const float* trow = tok + (size_t)gm * 1024;
    for (int j = t; j < 1024; j += 256) {
      sq[j] = trow[j];
      sp[j] = l ? trow[j - 1024] : 0.f;   // prev token row (guarded: no OOB at l==0)
    }
    __syncthreads();
    double qe0 = 0, qe1 = 0, qe2 = 0, qe3 = 0;
    double ke0 = 0, ke1 = 0, ke2 = 0, ke3 = 0;
    const float4* wq = (const float4*)Wqk + t;            // cols 4t..4t+3 of q-half
    const float4* wk = (const float4*)(Wqk + 1024) + t;   // cols 4t..4t+3 of k-half
#pragma unroll 4
    for (int d = 0; d < 1024; d++) {
      double td = (double)sq[d];
      double pd = (double)sp[d];
      float4 a = wq[(size_t)d * 512];     // Wqk[d][4t..4t+3]
      float4 b = wk[(size_t)d * 512];     // Wqk[d][1024+4t..]
      qe0 += td * (double)a.x; qe1 += td * (double)a.y;
      qe2 += td * (double)a.z; qe3 += td * (double)a.w;
      ke0 += pd * (double)b.x; ke1 += pd * (double)b.y;
      ke2 += pd * (double)b.z; ke3 += pd * (double)b.w;
    }
    if (l == 0) {
      float4 s4 = *((const float4*)sk + t);
      ke0 = (double)s4.x; ke1 = (double)s4.y;
      ke2 = (double)s4.z; ke3 = (double)s4.w;
    }
    double dq = qe0 * ke0 + qe1 * ke1 + qe2 * ke2 + qe3 * ke3;
    double nq = qe0 * qe0 + qe1 * qe1 + qe2 * qe2 + qe3 * qe3;
    double nk = ke0 * ke0 + ke1 * ke1 + ke2 * ke2 + ke3 * ke3;
#pragma unroll
    for (int off = 32; off > 0; off >>= 1) {
      dq += __shfl_down(dq, off);
      nq += __shfl_down(nq, off);
      nk += __shfl_down(nk, off);
    }
    int w = t >> 6;
    if ((t & 63) == 0) { red[0][w] = dq; red[1][w] = nq; red[2][w] = nk; }
    __syncthreads();
    if (t == 0) {
      double DQ = red[0][0] + red[0][1] + red[0][2] + red[0][3];
      double NQ = red[1][0] + red[1][1] + red[1][2] + red[1][3];
      double NK = red[2][0] + red[2][1] + red[2][2] + red[2][3];
      double den = sqrt(NQ) * sqrt(NK);
      if (den < 1e-8) den = 1e-8;
      probs[gm] = (float)(0.5 * (1.0 - DQ / den));
    }
    __syncthreads();   // sq/sp/red reused next iteration
  }
}

// ---------------------------------------------------------------------------
// meta: boundaries, chunk ids, compaction, num_chunks, aux per batch
// ---------------------------------------------------------------------------
__global__ __launch_bounds__(256) void meta_kernel(
    const float* __restrict__ probs, int* __restrict__ cid,
    int* __restrict__ pos, float* __restrict__ cprob,
    int* __restrict__ numC, float* __restrict__ auxv)
{
  __shared__ int   sc[256];
  __shared__ float psh[256];
  int b = blockIdx.x, t = threadIdx.x;
  const float* pr = probs + b * 4096;
  int base = t * 16;
  float pv[16]; int loc[16]; bool bd[16];
  int cnt = 0; float ps = 0.f;
#pragma unroll
  for (int i = 0; i < 16; i++) {
    float p = pr[base + i];
    pv[i] = p; ps += p;
    bool bb = (base + i == 0) || (p > 0.5f);
    bd[i] = bb; cnt += bb ? 1 : 0; loc[i] = cnt;
  }
  sc[t] = cnt; psh[t] = ps;
  __syncthreads();
  for (int off = 1; off < 256; off <<= 1) {
    int add = (t >= off) ? sc[t - off] : 0;
    __syncthreads();
    sc[t] += add;
    __syncthreads();
  }
  int excl = sc[t] - cnt;
#pragma unroll
  for (int i = 0; i < 16; i++) {
    int c = excl + loc[i] - 1;
    cid[b * 4096 + base + i] = c;
    if (bd[i]) { pos[b * 4096 + c] = base + i; cprob[b * 4096 + c] = pv[i]; }
  }
  int total = sc[255];
  for (int off = 128; off > 0; off >>= 1) {
    if (t < off) psh[t] += psh[t + off];
    __syncthreads();
  }
  if (t == 0) {
    numC[b] = total;
    float F = (float)total / 4096.f;
    float G = psh[0] / 4096.f;
    auxv[b] = 1.2f * (5.f * F * G + (1.f - F) * (1.f - G));
  }
}

__global__ void aux_final(const float* __restrict__ auxv, float* __restrict__ out2)
{
  if (threadIdx.x == 0) {
    float s = 0.f;
    for (int i = 0; i < 8; i++) s += auxv[i];
    out2[0] = s * (0.03f / 8.f);
  }
}

__global__ __launch_bounds__(256) void down_kernel(
    const float* __restrict__ tok, const int* __restrict__ pos,
    const float* __restrict__ cprob, const int* __restrict__ numC,
    float* __restrict__ out0)
{
  int blk = blockIdx.x;
  int b = blk >> 12, slot = blk & 4095;
  float4 v = make_float4(0.f, 0.f, 0.f, 0.f);
  if (slot < numC[b]) {
    int l = pos[blk];
    float p = cprob[blk];
    float4 tv = *(const float4*)(tok + (size_t)((b << 12) + l) * 1024 + threadIdx.x * 4);
    v = make_float4(p * tv.x, p * tv.y, p * tv.z, p * tv.w);
  }
  *(float4*)(out0 + (size_t)blk * 1024 + threadIdx.x * 4) = v;
}

// Segmented gated scan, 64-step warm-up (gates < 0.5 => error < 2^-64)
__global__ __launch_bounds__(256) void scanH_kernel(
    const float* __restrict__ out0, const float* __restrict__ cprob,
    const int* __restrict__ numC, float* __restrict__ H)
{
  int seg = blockIdx.x, b = blockIdx.y;
  int nc = numC[b];
  int cs = seg << 8;
  if (cs >= nc) return;
  int ce = min(cs + 256, nc);
  int c0 = (seg == 0) ? 0 : cs - 64;
  int off = threadIdx.x * 4;
  float hx = 0.f, hy = 0.f, hz = 0.f, hw = 0.f;
  int c = c0;
  for (; c < cs; c++) {
    float g = 1.f - cprob[(b << 12) + c];
    float4 xv = *(const float4*)(out0 + (size_t)((b << 12) + c) * 1024 + off);
    hx = fmaf(g, hx, xv.x); hy = fmaf(g, hy, xv.y);
    hz = fmaf(g, hz, xv.z); hw = fmaf(g, hw, xv.w);
  }
  for (; c < ce; c++) {
    float g = 1.f - cprob[(b << 12) + c];
    float4 xv = *(const float4*)(out0 + (size_t)((b << 12) + c) * 1024 + off);
    hx = fmaf(g, hx, xv.x); hy = fmaf(g, hy, xv.y);
    hz = fmaf(g, hz, xv.z); hw = fmaf(g, hw, xv.w);
    *(float4*)(H + (size_t)((b << 12) + c) * 1024 + off) = make_float4(hx, hy, hz, hw);
  }
}

// ---------------------------------------------------------------------------
extern "C" void kernel_launch(void* const* d_in, const int* in_sizes, int n_in,
                              void* d_out, int out_size, void* d_ws, size_t ws_size,
                              hipStream_t stream)
{
  const float* tokens = (const float*)d_in[0];
  const float* Wqk    = (const float*)d_in[1];
  const float* sk     = (const float*)d_in[2];
  const float* Wres   = (const float*)d_in[3];
  const float* bres   = (const float*)d_in[4];

  float* out0 = (float*)d_out;
  float* out1 = out0 + (size_t)M_ * D_;
  float* out2 = out1 + (size_t)M_ * D_;

  char* ws = (char*)d_ws;
  __half* C1h  = (__half*)ws;                          // [32768,2048] fp16 = 134MB
  float*  Hbuf = (float*)ws;                           // aliases C1h (dead after probs)
  u16* Tf  = (u16*)(ws + 134217728ull);                // 67MB fp16 tokens
  u16* Wf  = (u16*)(ws + 268435456ull);                // 4MB fp16 Wqk^T
  u16* Wf2 = (u16*)(ws + 272629760ull);                // 2MB fp16 Wres^T
  float* probs = (float*)(ws + 276824064ull);
  int*   cidp  = (int*)(ws + 276955136ull);
  int*   posp  = (int*)(ws + 277086208ull);
  float* cprob = (float*)(ws + 277217280ull);
  int*   numC  = (int*)(ws + 277348352ull);
  float* auxv  = (float*)(ws + 277348416ull);
  // flags/cnt live in out1: scratch until gemm mode-1 fully overwrites it,
  // and recheck2 (last reader) runs before that. NOT in C1h (probs reads it).
  int*   rflags = (int*)out1;
  int*   rcnt   = rflags + RCAP;

  // 1. fp16 casts (both weight casts up front; independent buffers)
  split_tok<<<16384, 256, 0, stream>>>(tokens, Tf);
  split_wT<<<1024, 256, 0, stream>>>(Wqk, 2048, Wf);
  split_wT<<<512, 256, 0, stream>>>(Wres, 1024, Wf2);
  zero_cnt<<<1, 64, 0, stream>>>(rcnt);
  // 2. qk projection: fp16 MFMA (BK=64) -> fp16 C1
  gemm_f16<<<4096, 256, 0, stream>>>(Tf, Wf, C1h, 2048, 16, 0,
                                     nullptr, nullptr, nullptr);
  // 3. cosine -> probs (+ fused near-threshold flag compaction)
  probs_half<<<8192, 256, 0, stream>>>(C1h, sk, probs, rflags, rcnt);
  // 4. fp64 re-check: one block per flagged position
  recheck2<<<512, 256, 0, stream>>>(tokens, Wqk, sk, probs, rflags, rcnt);
  // 5. boundaries / chunk ids / compaction / aux
  meta_kernel<<<8, 256, 0, stream>>>(probs, cidp, posp, cprob, numC, auxv);
  aux_final<<<1, 64, 0, stream>>>(auxv, out2);
  // 6. downsampled
  down_kernel<<<M_, 256, 0, stream>>>(tokens, posp, cprob, numC, out0);
  // 7. gated scan -> H (overwrites C1h region; safe: C1h dead after probs)
  scanH_kernel<<<dim3(16, 8), 256, 0, stream>>>(out0, cprob, numC, Hbuf);
  // 8. ups = tokens@Wres + H[cid] + bres (fp16 MFMA, fused epilogue;
  //    overwrites the flags scratch at the head of out1 -- flags are dead)
  gemm_f16<<<2048, 256, 0, stream>>>(Tf, Wf2, out1, 1024, 8, 1,
                                     Hbuf, cidp, bres);
}